// Round 1
// baseline (318.260 us; speedup 1.0000x reference)
//
#include <hip/hip_runtime.h>

// LSTM_67980742362036: 2-layer LSTM (B=4096, T=200, I=32, H=6) + linear head.
// Fused single kernel: one 64-thread block (1 wave) per batch element.
// Per 64-timestep chunk:
//   Phase P: lane = timestep; x-projection for layer 0 with W_ih0 via uniform
//            (SGPR) loads -> full 64-lane FMA efficiency. Result -> LDS.
//   Phase S: lanes 0..23 = layer-0 gate rows for step k, lanes 32..55 =
//            layer-1 gate rows for step k-1 (software pipeline; both consume
//            h1[k-1]). h/act exchanged through LDS; c-state in registers.
// 4096 blocks -> 16 waves/CU (4/SIMD) for latency hiding.

#define BATCH 4096
#define TLEN  200
#define ISZ   32
#define HSZ   6
#define GSZ   24      // 4*H
#define TCH   64      // timesteps per chunk
#define XPITCH 28     // padded LDS row stride (dwords): 16B-aligned rows, mild conflicts

__device__ __forceinline__ float fast_sig(float x) {
    // 1/(1+exp(-x)); v_exp + v_rcp. |rel err| ~1e-7, fine vs 3.7e-3 threshold.
    return __builtin_amdgcn_rcpf(1.0f + __expf(-x));
}

__global__ __launch_bounds__(64, 4) void lstm_fused(
    const float* __restrict__ x,
    const float* __restrict__ Wih0, const float* __restrict__ Whh0,
    const float* __restrict__ bih0, const float* __restrict__ bhh0,
    const float* __restrict__ Wih1, const float* __restrict__ Whh1,
    const float* __restrict__ bih1, const float* __restrict__ bhh1,
    const float* __restrict__ Wlin, const float* __restrict__ blin,
    float* __restrict__ out)
{
    __shared__ __align__(16) float xp_lds[TCH * XPITCH];  // layer-0 gate pre-acts, [t][r]
    __shared__ __align__(16) float sh_act[64];            // activated gates: [0..23]=L0, [32..55]=L1
    __shared__ __align__(16) float sh_h[16];              // h1 at [0..5], h2 at [8..13]

    const int lane = threadIdx.x;
    const int b   = blockIdx.x;

    // ---------------- scan-phase per-lane constants ----------------
    const bool isL0 = (lane < GSZ);
    const bool isL1 = (lane >= 32 && lane < 32 + GSZ);
    const int  r    = isL1 ? (lane - 32) : (isL0 ? lane : 0);

    float WA[HSZ], WB[HSZ];
    float base1 = 0.0f;
#pragma unroll
    for (int j = 0; j < HSZ; ++j) { WA[j] = 0.0f; WB[j] = 0.0f; }
    if (isL0) {
#pragma unroll
        for (int j = 0; j < HSZ; ++j) WA[j] = Whh0[r * HSZ + j];
    } else if (isL1) {
#pragma unroll
        for (int j = 0; j < HSZ; ++j) { WA[j] = Wih1[r * HSZ + j]; WB[j] = Whh1[r * HSZ + j]; }
        base1 = bih1[r] + bhh1[r];
    }
    // PyTorch gate order i,f,g,o: rows 12..17 are g -> tanh; tanh(x) = 2*sig(2x)-1
    const bool tanh_lane = (r >= 12 && r < 18);
    const float mg  = tanh_lane ? 2.0f : 1.0f;
    const float sg  = tanh_lane ? 2.0f : 1.0f;
    const float tgc = tanh_lane ? -1.0f : 0.0f;

    const bool updL    = (lane < HSZ) || (lane >= 32 && lane < 32 + HSZ);
    const int  uj      = (lane < 32) ? lane : (lane - 32);
    const int  actBase = (lane < 32) ? 0 : 32;
    const int  hSlot   = (lane < 32) ? 0 : 8;
    float c = 0.0f;  // cell state (layer 0 on lanes 0..5, layer 1 on lanes 32..37)

    if (lane < 16) sh_h[lane] = 0.0f;
    __syncthreads();

    for (int t0 = 0; t0 < TLEN; t0 += TCH) {
        const int tcl = min(TCH, TLEN - t0);

        // ---------------- Phase P: x-projection for this chunk ----------------
        {
            const int tclamp = min(t0 + lane, TLEN - 1);  // clamp tail (garbage rows never read)
            const float4* xrow = (const float4*)(x + ((size_t)b * TLEN + tclamp) * ISZ);
            float4 xr[8];
#pragma unroll
            for (int q = 0; q < 8; ++q) xr[q] = xrow[q];

            float acc[GSZ];
#pragma unroll
            for (int rr = 0; rr < GSZ; ++rr) {
                float a = bih0[rr] + bhh0[rr];               // uniform -> SGPR
                const float4* wrow = (const float4*)(Wih0 + rr * ISZ);  // uniform -> s_load
#pragma unroll
                for (int q = 0; q < 8; ++q) {
                    float4 w = wrow[q];
                    a += w.x * xr[q].x + w.y * xr[q].y + w.z * xr[q].z + w.w * xr[q].w;
                }
                acc[rr] = a;
            }
#pragma unroll
            for (int q = 0; q < 6; ++q) {
                *(float4*)&xp_lds[lane * XPITCH + 4 * q] =
                    make_float4(acc[4*q], acc[4*q+1], acc[4*q+2], acc[4*q+3]);
            }
        }
        __syncthreads();  // xp visible to scan readers

        // ---------------- Phase S: sequential scan over chunk ----------------
        const bool lastChunk = (t0 + TCH >= TLEN);
        const int  iters = tcl + (lastChunk ? 1 : 0);  // +1 drain iter for layer 1
        for (int it = 0; it < iters; ++it) {
            const int kg = t0 + it;            // global step index (L0 step; L1 does kg-1)
            const int kl = min(it, tcl - 1);   // clamped LDS row for drain iter
            __syncthreads();  // BAR-A: prev h-writes visible

            // broadcast reads (same address across lanes -> no conflicts)
            float4 h1a = *(const float4*)&sh_h[0];
            float2 h1b = *(const float2*)&sh_h[4];
            float4 h2a = *(const float4*)&sh_h[8];
            float2 h2b = *(const float2*)&sh_h[12];

            float g = isL0 ? xp_lds[kl * XPITCH + r] : base1;
            g += WA[0]*h1a.x + WA[1]*h1a.y + WA[2]*h1a.z + WA[3]*h1a.w
               + WA[4]*h1b.x + WA[5]*h1b.y;
            g += WB[0]*h2a.x + WB[1]*h2a.y + WB[2]*h2a.z + WB[3]*h2a.w
               + WB[4]*h2b.x + WB[5]*h2b.y;
            float a = sg * fast_sig(mg * g) + tgc;

            if (isL0 || isL1) sh_act[lane] = a;
            __syncthreads();  // BAR-B: acts visible to update lanes

            // L0 update valid for kg<T; L1 update valid for kg>=1 (drain/prologue guards)
            const bool active = updL && ((lane < 32) ? (kg < TLEN) : (kg >= 1));
            if (active) {
                float iv = sh_act[actBase + uj];
                float fv = sh_act[actBase + uj + 6];
                float gv = sh_act[actBase + uj + 12];
                float ov = sh_act[actBase + uj + 18];
                c = fv * c + iv * gv;
                float th = 2.0f * fast_sig(2.0f * c) - 1.0f;  // tanh(c)
                sh_h[hSlot + uj] = ov * th;
            }
        }
    }

    __syncthreads();
    if (lane == 0) {
        float s = blin[0];
#pragma unroll
        for (int j = 0; j < HSZ; ++j) s += Wlin[j] * sh_h[8 + j];
        out[b] = s;
    }
}

extern "C" void kernel_launch(void* const* d_in, const int* in_sizes, int n_in,
                              void* d_out, int out_size, void* d_ws, size_t ws_size,
                              hipStream_t stream) {
    const float* x    = (const float*)d_in[0];
    const float* Wih0 = (const float*)d_in[1];
    const float* Whh0 = (const float*)d_in[2];
    const float* bih0 = (const float*)d_in[3];
    const float* bhh0 = (const float*)d_in[4];
    const float* Wih1 = (const float*)d_in[5];
    const float* Whh1 = (const float*)d_in[6];
    const float* bih1 = (const float*)d_in[7];
    const float* bhh1 = (const float*)d_in[8];
    const float* Wlin = (const float*)d_in[9];
    const float* blin = (const float*)d_in[10];
    float* out = (float*)d_out;

    lstm_fused<<<BATCH, 64, 0, stream>>>(x, Wih0, Whh0, bih0, bhh0,
                                         Wih1, Whh1, bih1, bhh1,
                                         Wlin, blin, out);
}

// Round 2
// 296.536 us; speedup vs baseline: 1.0733x; 1.0733x over previous
//
#include <hip/hip_runtime.h>

// LSTM_67980742362036: 2-layer LSTM (B=4096, T=200, I=32, H=6) + linear head.
// One 64-thread block (1 wave) per batch element; 4096 blocks = 4 waves/SIMD.
//
// R2 change: barrier-free scan. The scan loop previously paid 2 x
// __syncthreads (full lgkmcnt(0) drains) + 2 LDS round-trips per step for
// tiny exchanges. Since the block is a single wave:
//   - h1 (lanes 0..5) / h2 (lanes 32..37) broadcast via v_readlane -> SGPR,
//     consumed directly as the scalar operand of v_fmac. No LDS, no barrier.
//   - i/f/g/o act gather to update lanes via 4 x ds_bpermute (precomputed
//     byte indices). All lanes compute c/h redundantly; only holder lanes'
//     values are ever read (via readlane), so no predication needed.
//   - xp (layer-0 input projection) read prefetched one step ahead.
// Remaining barriers: 2 per 64-step chunk around Phase P (8 total).

#define BATCH 4096
#define TLEN  200
#define ISZ   32
#define HSZ   6
#define GSZ   24      // 4*H
#define TCH   64      // timesteps per chunk (Phase P tile)
#define XPITCH 28     // padded LDS row stride (dwords)

__device__ __forceinline__ float fast_sig(float x) {
    // 1/(1+exp(-x)); v_exp + v_rcp. |rel err| ~1e-7 vs 3.7e-3 threshold.
    return __builtin_amdgcn_rcpf(1.0f + __expf(-x));
}
__device__ __forceinline__ float rl(float v, int l) {
    return __int_as_float(__builtin_amdgcn_readlane(__float_as_int(v), l));
}
__device__ __forceinline__ float bperm(int byteIdx, float v) {
    return __int_as_float(__builtin_amdgcn_ds_bpermute(byteIdx, __float_as_int(v)));
}

__global__ __launch_bounds__(64, 4) void lstm_fused(
    const float* __restrict__ x,
    const float* __restrict__ Wih0, const float* __restrict__ Whh0,
    const float* __restrict__ bih0, const float* __restrict__ bhh0,
    const float* __restrict__ Wih1, const float* __restrict__ Whh1,
    const float* __restrict__ bih1, const float* __restrict__ bhh1,
    const float* __restrict__ Wlin, const float* __restrict__ blin,
    float* __restrict__ out)
{
    __shared__ __align__(16) float xp_lds[TCH * XPITCH];  // L0 gate pre-acts [t][r]

    const int lane = threadIdx.x;
    const int b    = blockIdx.x;

    // ---------------- per-lane roles ----------------
    const bool loHalf = (lane < 32);
    const int  rr_    = loHalf ? lane : (lane - 32);
    const bool isL0   = loHalf && (rr_ < GSZ);
    const bool isL1   = !loHalf && (rr_ < GSZ);
    const int  r      = (rr_ < GSZ) ? rr_ : 0;   // idle lanes alias row 0 (broadcast read)

    float WA[HSZ], WB[HSZ];
    float base1 = 0.0f;
#pragma unroll
    for (int j = 0; j < HSZ; ++j) { WA[j] = 0.0f; WB[j] = 0.0f; }
    if (isL0) {
#pragma unroll
        for (int j = 0; j < HSZ; ++j) WA[j] = Whh0[r * HSZ + j];
    } else if (isL1) {
#pragma unroll
        for (int j = 0; j < HSZ; ++j) { WA[j] = Wih1[r * HSZ + j]; WB[j] = Whh1[r * HSZ + j]; }
        base1 = bih1[r] + bhh1[r];
    }
    // PyTorch gate order i,f,g,o: rows 12..17 are g -> tanh(x) = 2*sig(2x)-1
    const bool tanh_lane = (r >= 12 && r < 18);
    const float mg  = tanh_lane ? 2.0f : 1.0f;
    const float sg  = tanh_lane ? 2.0f : 1.0f;
    const float tgc = tanh_lane ? -1.0f : 0.0f;

    // bpermute byte indices: update lane j (= sel+j) gathers acts from rows
    // j, j+6, j+12, j+18 of its half. Other lanes compute garbage (never read).
    const int sel  = loHalf ? 0 : 32;
    const int jm   = (lane - sel) % HSZ;
    const int bi_i = (sel + jm) * 4;
    const int bi_f = (sel + jm + HSZ) * 4;
    const int bi_g = (sel + jm + 2 * HSZ) * 4;
    const int bi_o = (sel + jm + 3 * HSZ) * 4;

    float c = 0.0f, h = 0.0f;   // lanes 0..5: (c1,h1); lanes 32..37: (c2,h2)

    for (int t0 = 0; t0 < TLEN; t0 += TCH) {
        const int tcl = min(TCH, TLEN - t0);
        __syncthreads();  // previous chunk's scan reads done before overwrite

        // ---------------- Phase P: x-projection for this chunk ----------------
        {
            const int tclamp = min(t0 + lane, TLEN - 1);  // clamped tail rows never read
            const float4* xrow = (const float4*)(x + ((size_t)b * TLEN + tclamp) * ISZ);
            float4 xr[8];
#pragma unroll
            for (int q = 0; q < 8; ++q) xr[q] = xrow[q];

            float acc[GSZ];
#pragma unroll
            for (int rrr = 0; rrr < GSZ; ++rrr) {
                float a = bih0[rrr] + bhh0[rrr];                       // uniform
                const float4* wrow = (const float4*)(Wih0 + rrr * ISZ); // uniform -> s_load
#pragma unroll
                for (int q = 0; q < 8; ++q) {
                    float4 w = wrow[q];
                    a += w.x * xr[q].x + w.y * xr[q].y + w.z * xr[q].z + w.w * xr[q].w;
                }
                acc[rrr] = a;
            }
#pragma unroll
            for (int q = 0; q < 6; ++q) {
                *(float4*)&xp_lds[lane * XPITCH + 4 * q] =
                    make_float4(acc[4*q], acc[4*q+1], acc[4*q+2], acc[4*q+3]);
            }
        }
        __syncthreads();  // xp visible to scan

        // ---------------- Phase S: barrier-free scan ----------------
        const bool lastChunk = (t0 + TCH >= TLEN);
        const int  iters = tcl + (lastChunk ? 1 : 0);   // +1 drain iter for layer 1
        float xp_cur = xp_lds[r];                        // it = 0 row
        for (int it = 0; it < iters; ++it) {
            const int kg = t0 + it;

            // h broadcast: register state of holder lanes -> SGPRs
            const float h10 = rl(h, 0),  h11 = rl(h, 1),  h12 = rl(h, 2);
            const float h13 = rl(h, 3),  h14 = rl(h, 4),  h15 = rl(h, 5);
            const float h20 = rl(h, 32), h21 = rl(h, 33), h22 = rl(h, 34);
            const float h23 = rl(h, 35), h24 = rl(h, 36), h25 = rl(h, 37);

            // prefetch next iteration's xp row (latency hidden under gate math)
            const int kn = min(it + 1, tcl - 1);
            const float xp_nxt = xp_lds[kn * XPITCH + r];

            // gate pre-activation (uniform 12-fmac block, 4 parallel chains)
            const float g0 = loHalf ? xp_cur : base1;
            float a0 = fmaf(WA[0], h10, fmaf(WA[2], h12, fmaf(WA[4], h14, g0)));
            float a1 = fmaf(WA[1], h11, fmaf(WA[3], h13, WA[5] * h15));
            float b0 = fmaf(WB[0], h20, fmaf(WB[2], h22, WB[4] * h24));
            float b1 = fmaf(WB[1], h21, fmaf(WB[3], h23, WB[5] * h25));
            const float g = (a0 + a1) + (b0 + b1);
            const float a = fmaf(sg, fast_sig(mg * g), tgc);

            // gather i,f,g,o to update lanes (in-register, no barrier)
            const float iv = bperm(bi_i, a);
            const float fv = bperm(bi_f, a);
            const float gv = bperm(bi_g, a);
            const float ov = bperm(bi_o, a);

            // cell/hidden update (all lanes; only holder lanes' values read)
            const float cn = fmaf(fv, c, iv * gv);
            const float th = fmaf(2.0f, fast_sig(2.0f * cn), -1.0f);  // tanh(cn)
            const float hn = ov * th;

            // guard: L1 state must not absorb the kg==0 phantom step.
            // (L0's drain-step garbage update is never read -> unguarded.)
            const bool ok = loHalf || (kg >= 1);
            c = ok ? cn : c;
            h = ok ? hn : h;

            xp_cur = xp_nxt;
        }
    }

    // Linear head on final h2 (lanes 32..37), uniform via readlane.
    float s = blin[0];
#pragma unroll
    for (int j = 0; j < HSZ; ++j) s = fmaf(Wlin[j], rl(h, 32 + j), s);
    if (lane == 0) out[b] = s;
}

extern "C" void kernel_launch(void* const* d_in, const int* in_sizes, int n_in,
                              void* d_out, int out_size, void* d_ws, size_t ws_size,
                              hipStream_t stream) {
    const float* x    = (const float*)d_in[0];
    const float* Wih0 = (const float*)d_in[1];
    const float* Whh0 = (const float*)d_in[2];
    const float* bih0 = (const float*)d_in[3];
    const float* bhh0 = (const float*)d_in[4];
    const float* Wih1 = (const float*)d_in[5];
    const float* Whh1 = (const float*)d_in[6];
    const float* bih1 = (const float*)d_in[7];
    const float* bhh1 = (const float*)d_in[8];
    const float* Wlin = (const float*)d_in[9];
    const float* blin = (const float*)d_in[10];
    float* out = (float*)d_out;

    lstm_fused<<<BATCH, 64, 0, stream>>>(x, Wih0, Whh0, bih0, bhh0,
                                         Wih1, Whh1, bih1, bhh1,
                                         Wlin, blin, out);
}

// Round 3
// 288.684 us; speedup vs baseline: 1.1025x; 1.0272x over previous
//
#include <hip/hip_runtime.h>

// LSTM_67980742362036: 2-layer LSTM (B=4096, T=200, I=32, H=6) + linear head.
// One 64-thread block (1 wave) per batch element; 4096 blocks = 4 waves/SIMD.
//
// R3 change: eliminate register spills (R2 showed WRITE_SIZE=28.8MB vs 16KB
// legitimate -> ~7KB/block scratch traffic; VGPR_Count=64 with Phase P
// needing ~70 live regs when fully unrolled).
//   - Phase P computes gate rows in 3 groups of 8: acc[8] dies into its LDS
//     store before the next group -> live set ~50 VGPRs, no spill.
//   - amdgpu_waves_per_eu(4,4): grid caps us at 4 waves/SIMD anyway, so give
//     the allocator the full 128-VGPR budget instead of its 8-wave target.
//   - xp_lds gets a 65th row so the scan's prefetch address is a pure
//     induction (row = it+1, unconditional; garbage row never consumed).
// Scan stays the R2 barrier-free readlane/bpermute form.

#define BATCH 4096
#define TLEN  200
#define ISZ   32
#define HSZ   6
#define GSZ   24      // 4*H
#define TCH   64      // timesteps per chunk (Phase P tile)
#define XPITCH 28     // padded LDS row stride (dwords)
#define XROWS (TCH + 1)  // +1 garbage row for unconditional prefetch

__device__ __forceinline__ float fast_sig(float x) {
    // 1/(1+exp(-x)); v_exp + v_rcp. |rel err| ~1e-7 vs 3.7e-3 threshold.
    return __builtin_amdgcn_rcpf(1.0f + __expf(-x));
}
__device__ __forceinline__ float rl(float v, int l) {
    return __int_as_float(__builtin_amdgcn_readlane(__float_as_int(v), l));
}
__device__ __forceinline__ float bperm(int byteIdx, float v) {
    return __int_as_float(__builtin_amdgcn_ds_bpermute(byteIdx, __float_as_int(v)));
}

__global__ void __launch_bounds__(64)
__attribute__((amdgpu_waves_per_eu(4, 4)))
lstm_fused(
    const float* __restrict__ x,
    const float* __restrict__ Wih0, const float* __restrict__ Whh0,
    const float* __restrict__ bih0, const float* __restrict__ bhh0,
    const float* __restrict__ Wih1, const float* __restrict__ Whh1,
    const float* __restrict__ bih1, const float* __restrict__ bhh1,
    const float* __restrict__ Wlin, const float* __restrict__ blin,
    float* __restrict__ out)
{
    __shared__ __align__(16) float xp_lds[XROWS * XPITCH];  // L0 gate pre-acts [t][r]

    const int lane = threadIdx.x;
    const int b    = blockIdx.x;

    // ---------------- per-lane roles ----------------
    const bool loHalf = (lane < 32);
    const int  rr_    = loHalf ? lane : (lane - 32);
    const bool isL0   = loHalf && (rr_ < GSZ);
    const bool isL1   = !loHalf && (rr_ < GSZ);
    const int  r      = (rr_ < GSZ) ? rr_ : 0;   // idle lanes alias row 0 (broadcast read)

    float WA[HSZ], WB[HSZ];
    float base1 = 0.0f;
#pragma unroll
    for (int j = 0; j < HSZ; ++j) { WA[j] = 0.0f; WB[j] = 0.0f; }
    if (isL0) {
#pragma unroll
        for (int j = 0; j < HSZ; ++j) WA[j] = Whh0[r * HSZ + j];
    } else if (isL1) {
#pragma unroll
        for (int j = 0; j < HSZ; ++j) { WA[j] = Wih1[r * HSZ + j]; WB[j] = Whh1[r * HSZ + j]; }
        base1 = bih1[r] + bhh1[r];
    }
    // PyTorch gate order i,f,g,o: rows 12..17 are g -> tanh(x) = 2*sig(2x)-1
    const bool tanh_lane = (r >= 12 && r < 18);
    const float mg  = tanh_lane ? 2.0f : 1.0f;
    const float sg  = tanh_lane ? 2.0f : 1.0f;
    const float tgc = tanh_lane ? -1.0f : 0.0f;

    // bpermute byte indices: update lane j (= sel+j) gathers acts from rows
    // j, j+6, j+12, j+18 of its half. Other lanes compute garbage (never read).
    const int sel  = loHalf ? 0 : 32;
    const int jm   = (lane - sel) % HSZ;
    const int bi_i = (sel + jm) * 4;
    const int bi_f = (sel + jm + HSZ) * 4;
    const int bi_g = (sel + jm + 2 * HSZ) * 4;
    const int bi_o = (sel + jm + 3 * HSZ) * 4;

    float c = 0.0f, h = 0.0f;   // lanes 0..5: (c1,h1); lanes 32..37: (c2,h2)

    for (int t0 = 0; t0 < TLEN; t0 += TCH) {
        const int tcl = min(TCH, TLEN - t0);
        __syncthreads();  // previous chunk's scan reads done before overwrite

        // ---------------- Phase P: x-projection for this chunk ----------------
        // 3 groups of 8 rows: acc[8] dies into its LDS store -> no spills.
        {
            const int tclamp = min(t0 + lane, TLEN - 1);  // clamped tail rows never read
            const float4* xrow = (const float4*)(x + ((size_t)b * TLEN + tclamp) * ISZ);
            float4 xr[8];
#pragma unroll
            for (int q = 0; q < 8; ++q) xr[q] = xrow[q];

#pragma unroll
            for (int grp = 0; grp < 3; ++grp) {
                float acc[8];
#pragma unroll
                for (int rr = 0; rr < 8; ++rr) {
                    const int row = grp * 8 + rr;
                    float a = bih0[row] + bhh0[row];                       // uniform -> SGPR
                    const float4* wrow = (const float4*)(Wih0 + row * ISZ); // uniform -> s_load
#pragma unroll
                    for (int q = 0; q < 8; ++q) {
                        float4 w = wrow[q];
                        a += w.x * xr[q].x + w.y * xr[q].y + w.z * xr[q].z + w.w * xr[q].w;
                    }
                    acc[rr] = a;
                }
                *(float4*)&xp_lds[lane * XPITCH + 8 * grp] =
                    make_float4(acc[0], acc[1], acc[2], acc[3]);
                *(float4*)&xp_lds[lane * XPITCH + 8 * grp + 4] =
                    make_float4(acc[4], acc[5], acc[6], acc[7]);
            }
        }
        __syncthreads();  // xp visible to scan

        // ---------------- Phase S: barrier-free scan ----------------
        const bool lastChunk = (t0 + TCH >= TLEN);
        const int  iters = tcl + (lastChunk ? 1 : 0);   // +1 drain iter for layer 1
        float xp_cur = xp_lds[r];                        // row 0
        for (int it = 0; it < iters; ++it) {
            const int kg = t0 + it;

            // h broadcast: register state of holder lanes -> SGPRs
            const float h10 = rl(h, 0),  h11 = rl(h, 1),  h12 = rl(h, 2);
            const float h13 = rl(h, 3),  h14 = rl(h, 4),  h15 = rl(h, 5);
            const float h20 = rl(h, 32), h21 = rl(h, 33), h22 = rl(h, 34);
            const float h23 = rl(h, 35), h24 = rl(h, 36), h25 = rl(h, 37);

            // prefetch next row unconditionally (row iters<=65 allocated;
            // final prefetch is garbage, never consumed). Pure induction addr.
            const float xp_nxt = xp_lds[(it + 1) * XPITCH + r];

            // gate pre-activation (4 parallel fma chains)
            const float g0 = loHalf ? xp_cur : base1;
            float a0 = fmaf(WA[0], h10, fmaf(WA[2], h12, fmaf(WA[4], h14, g0)));
            float a1 = fmaf(WA[1], h11, fmaf(WA[3], h13, WA[5] * h15));
            float b0 = fmaf(WB[0], h20, fmaf(WB[2], h22, WB[4] * h24));
            float b1 = fmaf(WB[1], h21, fmaf(WB[3], h23, WB[5] * h25));
            const float g = (a0 + a1) + (b0 + b1);
            const float a = fmaf(sg, fast_sig(mg * g), tgc);

            // gather i,f,g,o to update lanes (in-register, no barrier)
            const float iv = bperm(bi_i, a);
            const float fv = bperm(bi_f, a);
            const float gv = bperm(bi_g, a);
            const float ov = bperm(bi_o, a);

            // cell/hidden update (all lanes; only holder lanes' values read)
            const float cn = fmaf(fv, c, iv * gv);
            const float th = fmaf(2.0f, fast_sig(2.0f * cn), -1.0f);  // tanh(cn)
            const float hn = ov * th;

            // guard: L1 state must not absorb the kg==0 phantom step.
            // (L0's drain-step garbage update is never read -> unguarded.)
            const bool ok = loHalf || (kg >= 1);
            c = ok ? cn : c;
            h = ok ? hn : h;

            xp_cur = xp_nxt;
        }
    }

    // Linear head on final h2 (lanes 32..37), uniform via readlane.
    float s = blin[0];
#pragma unroll
    for (int j = 0; j < HSZ; ++j) s = fmaf(Wlin[j], rl(h, 32 + j), s);
    if (lane == 0) out[b] = s;
}

extern "C" void kernel_launch(void* const* d_in, const int* in_sizes, int n_in,
                              void* d_out, int out_size, void* d_ws, size_t ws_size,
                              hipStream_t stream) {
    const float* x    = (const float*)d_in[0];
    const float* Wih0 = (const float*)d_in[1];
    const float* Whh0 = (const float*)d_in[2];
    const float* bih0 = (const float*)d_in[3];
    const float* bhh0 = (const float*)d_in[4];
    const float* Wih1 = (const float*)d_in[5];
    const float* Whh1 = (const float*)d_in[6];
    const float* bih1 = (const float*)d_in[7];
    const float* bhh1 = (const float*)d_in[8];
    const float* Wlin = (const float*)d_in[9];
    const float* blin = (const float*)d_in[10];
    float* out = (float*)d_out;

    lstm_fused<<<BATCH, 64, 0, stream>>>(x, Wih0, Whh0, bih0, bhh0,
                                         Wih1, Whh1, bih1, bhh1,
                                         Wlin, blin, out);
}